// Round 1
// baseline (184.269 us; speedup 1.0000x reference)
//
#include <hip/hip_runtime.h>
#include <hip/hip_bf16.h>

#define N_NODES 50000
#define N_EDGES 600000
#define IN_F 256
#define OUT_F 128
#define SCAN_BLOCKS 196    // ceil(50000/256)
#define GEMM_BLOCKS 196    // 256 rows per block
#define HIST_BLOCKS 1172   // ceil(600000/512)

typedef __bf16 bf16x8 __attribute__((ext_vector_type(8)));
typedef __bf16 bf16x2 __attribute__((ext_vector_type(2)));
typedef float  f32x4  __attribute__((ext_vector_type(4)));

__device__ __forceinline__ void async_copy16(void* lds, const void* g) {
    __builtin_amdgcn_global_load_lds(
        (const __attribute__((address_space(1))) void*)g,
        (__attribute__((address_space(3))) void*)lds, 16, 0, 0);
}

// ---------------------------------------------------------------------------
// Kernel 0: prep. (a) counts[] = 0 (replaces hipMemsetAsync);
// (b) wt_sw = bf16 W^T, pre-swizzled so that a LINEAR 64KB LDS copy yields
// the XOR-swizzled layout the GEMM fragment reads expect:
//   LDS byte (n<<9) + (2k ^ ((n&7)<<4)) holds bf16(w[k][n])
//   -> element i of wt_sw: n = i>>8, k = (i&255) ^ ((n&7)<<3).
// Swizzle spreads the 16 fragment rows across 8 bank-groups (2-way = free).
// ---------------------------------------------------------------------------
__global__ __launch_bounds__(256) void gcn_prep(const float* __restrict__ w,
                                                __bf16* __restrict__ wt_sw,
                                                int* __restrict__ counts) {
    int i = blockIdx.x * 256 + threadIdx.x;
    if (i < IN_F * OUT_F) {
        int n = i >> 8;                          // 0..127 (output col)
        int k = (i & 255) ^ ((n & 7) << 3);      // 0..255 (input feature)
        wt_sw[i] = (__bf16)w[k * OUT_F + n];
    } else {
        int j = i - IN_F * OUT_F;
        if (j < N_NODES) counts[j] = 0;
    }
}

// ---------------------------------------------------------------------------
// Kernel 1 (fused): blocks [0,196) = GEMM  support = bf16(x @ W);
//                   blocks [196,1368) = histogram rank[e] = counts[erows[e]]++.
// GEMM: 512 thr = 8 waves x 32 rows.
//  - W^T staged via 8x global_load_lds_dwordx4 (async DMA, no VGPR roundtrip,
//    no conversion, no conflicted transposed writes).
//  - x loads double-buffered in registers (prefetch next ks before MFMAs) to
//    double VMEM-in-flight: the kernel was latency-bound at 1.44 TB/s.
//  - epilogue: acc -> LDS (reuse W buffer, XOR-swizzled bf16 [256][128]) ->
//    coalesced dwordx4 stores (kills the 2.2x partial-line write blowup).
// __launch_bounds__(512,4): cap VGPR at 128 so 2 blocks/CU survive prefetch.
// ---------------------------------------------------------------------------
__global__ __launch_bounds__(512, 4) void gcn_gemm_hist(const float* __restrict__ x,
                                                        const __bf16* __restrict__ wt_sw,
                                                        __bf16* __restrict__ support,
                                                        const int* __restrict__ erows,
                                                        int* __restrict__ counts,
                                                        int* __restrict__ rank) {
    __shared__ char smem[65536];   // W^T bf16 (swizzled) during K-loop; C-tile in epilogue
    const int t = threadIdx.x;

    if (blockIdx.x >= GEMM_BLOCKS) {
        // ---------------- histogram part ----------------
        int e = (blockIdx.x - GEMM_BLOCKS) * 512 + t;
        if (e < N_EDGES) rank[e] = atomicAdd(&counts[erows[e]], 1);
        return;
    }

    // ---------------- GEMM part ----------------
    const int wave = t >> 6;                         // 0..7
    const int lane = t & 63;
    const int m    = lane & 15;
    const int quad = lane >> 4;

    // stage 64KB W^T: linear LDS dest, 8 iters x (8 waves x 64 lanes x 16B)
    {
        const char* gW = (const char*)wt_sw + wave * 1024 + lane * 16;
        char* lW = smem + wave * 1024;               // wave-uniform base
#pragma unroll
        for (int it = 0; it < 8; it++)
            async_copy16(lW + it * 8192, gW + it * 8192);
    }
    __syncthreads();   // drains vmcnt(0) for the global_load_lds queue

    const int row0 = blockIdx.x * 256 + wave * 32;
    int r0 = row0 + m;
    int r1 = row0 + 16 + m;
    const float* xp0 = x + (size_t)(r0 < N_NODES ? r0 : 0) * IN_F + quad * 8;
    const float* xp1 = x + (size_t)(r1 < N_NODES ? r1 : 0) * IN_F + quad * 8;

    f32x4 acc0[8], acc1[8];
#pragma unroll
    for (int nt = 0; nt < 8; nt++) {
        acc0[nt] = (f32x4){0.f, 0.f, 0.f, 0.f};
        acc1[nt] = (f32x4){0.f, 0.f, 0.f, 0.f};
    }

    // prime ks=0
    float4 c00 = *(const float4*)(xp0);
    float4 c01 = *(const float4*)(xp0 + 4);
    float4 c10 = *(const float4*)(xp1);
    float4 c11 = *(const float4*)(xp1 + 4);

#pragma unroll
    for (int ks = 0; ks < 8; ks++) {
        // prefetch ks+1 before the MFMA cluster (latency hides under MFMAs)
        float4 n00, n01, n10, n11;
        if (ks < 7) {
            n00 = *(const float4*)(xp0 + (ks + 1) * 32);
            n01 = *(const float4*)(xp0 + (ks + 1) * 32 + 4);
            n10 = *(const float4*)(xp1 + (ks + 1) * 32);
            n11 = *(const float4*)(xp1 + (ks + 1) * 32 + 4);
        }
        bf16x8 af0 = { (__bf16)c00.x, (__bf16)c00.y, (__bf16)c00.z, (__bf16)c00.w,
                       (__bf16)c01.x, (__bf16)c01.y, (__bf16)c01.z, (__bf16)c01.w };
        bf16x8 af1 = { (__bf16)c10.x, (__bf16)c10.y, (__bf16)c10.z, (__bf16)c10.w,
                       (__bf16)c11.x, (__bf16)c11.y, (__bf16)c11.z, (__bf16)c11.w };
#pragma unroll
        for (int nt = 0; nt < 8; nt++) {
            int nrow = nt * 16 + m;
            const bf16x8 bf = *(const bf16x8*)(smem + (nrow << 9) +
                                ((ks * 64 + quad * 16) ^ ((nrow & 7) << 4)));
            acc0[nt] = __builtin_amdgcn_mfma_f32_16x16x32_bf16(af0, bf, acc0[nt], 0, 0, 0);
            acc1[nt] = __builtin_amdgcn_mfma_f32_16x16x32_bf16(af1, bf, acc1[nt], 0, 0, 0);
        }
        if (ks < 7) { c00 = n00; c01 = n01; c10 = n10; c11 = n11; }
    }

    // ---- epilogue: transpose through LDS, then full-line vector stores ----
    __syncthreads();   // all waves done reading W from smem
#pragma unroll
    for (int nt = 0; nt < 8; nt++) {
        int cb = (nt * 16 + m) * 2;                  // col byte offset
#pragma unroll
        for (int r = 0; r < 4; r++) {
            int lr0 = wave * 32 + quad * 4 + r;      // C/D layout [m89]: row=quad*4+r
            int lr1 = lr0 + 16;
            *(__bf16*)(smem + (lr0 << 8) + (cb ^ ((lr0 & 7) << 4))) = (__bf16)acc0[nt][r];
            *(__bf16*)(smem + (lr1 << 8) + (cb ^ ((lr1 & 7) << 4))) = (__bf16)acc1[nt][r];
        }
    }
    __syncthreads();
    {
        int row  = t >> 1;                           // 0..255
        int half = t & 1;
        int g = blockIdx.x * 256 + row;
        if (g < N_NODES) {
            char* dst = (char*)(support + (size_t)g * OUT_F) + half * 128;
#pragma unroll
            for (int j = 0; j < 8; j++) {
                int boff = (half * 128 + j * 16) ^ ((row & 7) << 4);
                *(bf16x8*)(dst + j * 16) = *(const bf16x8*)(smem + (row << 8) + boff);
            }
        }
    }
}

// ---------------------------------------------------------------------------
// Kernel 2: per-block exclusive scan of counts -> block-local row_start +
// per-block totals in partials.
// ---------------------------------------------------------------------------
__global__ __launch_bounds__(256) void gcn_scan1(const int* __restrict__ counts,
                                                 int* __restrict__ row_start,
                                                 int* __restrict__ partials) {
    __shared__ int s[256];
    const int t = threadIdx.x;
    const int i = blockIdx.x * 256 + t;
    int v = (i < N_NODES) ? counts[i] : 0;
    s[t] = v;
    __syncthreads();
#pragma unroll
    for (int off = 1; off < 256; off <<= 1) {
        int x = (t >= off) ? s[t - off] : 0;
        __syncthreads();
        s[t] += x;
        __syncthreads();
    }
    if (i < N_NODES) row_start[i] = s[t] - v;     // block-local exclusive
    if (t == 255) partials[blockIdx.x] = s[255];
}

// ---------------------------------------------------------------------------
// Kernel 3: single-block scan of the 196 partials -> absolute block prefix.
// Removes the redundant 256-wide scan from every scatter/aggregate block.
// ---------------------------------------------------------------------------
__global__ __launch_bounds__(256) void gcn_scan2(const int* __restrict__ partials,
                                                 int* __restrict__ bp) {
    __shared__ int s[256];
    const int t = threadIdx.x;
    int v = (t < SCAN_BLOCKS) ? partials[t] : 0;
    s[t] = v;
    __syncthreads();
#pragma unroll
    for (int off = 1; off < 256; off <<= 1) {
        int x = (t >= off) ? s[t - off] : 0;
        __syncthreads();
        s[t] += x;
        __syncthreads();
    }
    if (t < SCAN_BLOCKS) bp[t] = s[t];            // inclusive prefix
}

// ---------------------------------------------------------------------------
// Kernel 4: packed scatter. pos = local_rs + bp[blk-1] + rank. No LDS.
// ---------------------------------------------------------------------------
__global__ __launch_bounds__(512) void gcn_scatter(const int* __restrict__ erows,
                                                   const int* __restrict__ ecols,
                                                   const float* __restrict__ evals,
                                                   const int* __restrict__ row_start,
                                                   const int* __restrict__ rank,
                                                   const int* __restrict__ bp,
                                                   int2* __restrict__ sorted_cv) {
    int e = blockIdx.x * 512 + threadIdx.x;
    if (e >= N_EDGES) return;
    int r = erows[e];
    int blk = r >> 8;
    int add = blk ? bp[blk - 1] : 0;
    int pos = row_start[r] + add + rank[e];
    sorted_cv[pos] = make_int2(ecols[e], __float_as_int(evals[e]));
}

// ---------------------------------------------------------------------------
// Kernel 5: aggregate. One wave per node; bf16x2/lane covers 128 cols.
// Absolute beg/end via precomputed bp. Unroll-8 (MLP=8). No LDS.
// out[n] = bias + sum_{e in row n} val_e * support[col_e]
// ---------------------------------------------------------------------------
__global__ __launch_bounds__(512) void gcn_aggregate_csr(const __bf16* __restrict__ support,
                                                         const int2* __restrict__ sorted_cv,
                                                         const int* __restrict__ row_start,
                                                         const int* __restrict__ bp,
                                                         const float* __restrict__ bias,
                                                         float* __restrict__ out) {
    const int t = threadIdx.x;
    const int node = (blockIdx.x * 512 + t) >> 6;
    const int lane = t & 63;
    if (node >= N_NODES) return;

    int blk = node >> 8;
    const int beg = row_start[node] + (blk ? bp[blk - 1] : 0);
    int end;
    if (node + 1 < N_NODES) {
        int blk1 = (node + 1) >> 8;
        end = row_start[node + 1] + (blk1 ? bp[blk1 - 1] : 0);
    } else {
        end = N_EDGES;
    }

    float2 accA = *(const float2*)&bias[lane * 2];
    float2 accB = make_float2(0.f, 0.f);
    const __bf16* sp = support + lane * 2;

    int i = beg;
    for (; i + 7 < end; i += 8) {
        int2 cv0 = sorted_cv[i];
        int2 cv1 = sorted_cv[i + 1];
        int2 cv2 = sorted_cv[i + 2];
        int2 cv3 = sorted_cv[i + 3];
        int2 cv4 = sorted_cv[i + 4];
        int2 cv5 = sorted_cv[i + 5];
        int2 cv6 = sorted_cv[i + 6];
        int2 cv7 = sorted_cv[i + 7];
        bf16x2 s0 = *(const bf16x2*)(sp + (size_t)cv0.x * OUT_F);
        bf16x2 s1 = *(const bf16x2*)(sp + (size_t)cv1.x * OUT_F);
        bf16x2 s2 = *(const bf16x2*)(sp + (size_t)cv2.x * OUT_F);
        bf16x2 s3 = *(const bf16x2*)(sp + (size_t)cv3.x * OUT_F);
        bf16x2 s4 = *(const bf16x2*)(sp + (size_t)cv4.x * OUT_F);
        bf16x2 s5 = *(const bf16x2*)(sp + (size_t)cv5.x * OUT_F);
        bf16x2 s6 = *(const bf16x2*)(sp + (size_t)cv6.x * OUT_F);
        bf16x2 s7 = *(const bf16x2*)(sp + (size_t)cv7.x * OUT_F);
        accA.x += __int_as_float(cv0.y) * (float)s0.x + __int_as_float(cv1.y) * (float)s1.x;
        accA.y += __int_as_float(cv0.y) * (float)s0.y + __int_as_float(cv1.y) * (float)s1.y;
        accB.x += __int_as_float(cv2.y) * (float)s2.x + __int_as_float(cv3.y) * (float)s3.x;
        accB.y += __int_as_float(cv2.y) * (float)s2.y + __int_as_float(cv3.y) * (float)s3.y;
        accA.x += __int_as_float(cv4.y) * (float)s4.x + __int_as_float(cv5.y) * (float)s5.x;
        accA.y += __int_as_float(cv4.y) * (float)s4.y + __int_as_float(cv5.y) * (float)s5.y;
        accB.x += __int_as_float(cv6.y) * (float)s6.x + __int_as_float(cv7.y) * (float)s7.x;
        accB.y += __int_as_float(cv6.y) * (float)s6.y + __int_as_float(cv7.y) * (float)s7.y;
    }
    for (; i + 3 < end; i += 4) {
        int2 cv0 = sorted_cv[i];
        int2 cv1 = sorted_cv[i + 1];
        int2 cv2 = sorted_cv[i + 2];
        int2 cv3 = sorted_cv[i + 3];
        bf16x2 s0 = *(const bf16x2*)(sp + (size_t)cv0.x * OUT_F);
        bf16x2 s1 = *(const bf16x2*)(sp + (size_t)cv1.x * OUT_F);
        bf16x2 s2 = *(const bf16x2*)(sp + (size_t)cv2.x * OUT_F);
        bf16x2 s3 = *(const bf16x2*)(sp + (size_t)cv3.x * OUT_F);
        accA.x += __int_as_float(cv0.y) * (float)s0.x + __int_as_float(cv1.y) * (float)s1.x;
        accA.y += __int_as_float(cv0.y) * (float)s0.y + __int_as_float(cv1.y) * (float)s1.y;
        accB.x += __int_as_float(cv2.y) * (float)s2.x + __int_as_float(cv3.y) * (float)s3.x;
        accB.y += __int_as_float(cv2.y) * (float)s2.y + __int_as_float(cv3.y) * (float)s3.y;
    }
    for (; i < end; i++) {
        int2 cv = sorted_cv[i];
        float v = __int_as_float(cv.y);
        bf16x2 sv = *(const bf16x2*)(sp + (size_t)cv.x * OUT_F);
        accA.x += v * (float)sv.x;
        accA.y += v * (float)sv.y;
    }
    accA.x += accB.x;
    accA.y += accB.y;

    *(float2*)&out[(size_t)node * OUT_F + lane * 2] = accA;
}

// ---------------------------------------------------------------------------
static inline size_t align_up(size_t v, size_t a) { return (v + a - 1) & ~(a - 1); }

extern "C" void kernel_launch(void* const* d_in, const int* in_sizes, int n_in,
                              void* d_out, int out_size, void* d_ws, size_t ws_size,
                              hipStream_t stream) {
    const float* x     = (const float*)d_in[0];   // [50000, 256]
    const int*   erows = (const int*)d_in[1];     // [600000]
    const int*   ecols = (const int*)d_in[2];     // [600000]
    const float* evals = (const float*)d_in[3];   // [600000]
    const float* w     = (const float*)d_in[4];   // [256, 128]
    const float* bias  = (const float*)d_in[5];   // [128]
    float* out = (float*)d_out;                   // [50000, 128]

    // workspace layout (all regions 64B-aligned; ~20.7 MB total)
    size_t off = 0;
    __bf16* support   = (__bf16*)((char*)d_ws + off);
    off = align_up(off + (size_t)N_NODES * OUT_F * 2, 64);
    int*    counts    = (int*)((char*)d_ws + off);
    off = align_up(off + (size_t)N_NODES * 4, 64);
    int*    row_start = (int*)((char*)d_ws + off);
    off = align_up(off + (size_t)N_NODES * 4, 64);
    int*    rank      = (int*)((char*)d_ws + off);
    off = align_up(off + (size_t)N_EDGES * 4, 64);
    int*    partials  = (int*)((char*)d_ws + off);
    off = align_up(off + 256 * 4, 64);
    int*    bp        = (int*)((char*)d_ws + off);
    off = align_up(off + 256 * 4, 64);
    __bf16* wt_sw     = (__bf16*)((char*)d_ws + off);
    off = align_up(off + (size_t)IN_F * OUT_F * 2, 64);
    int2*   sorted_cv = (int2*)((char*)d_ws + off);

    const int eblocks512 = (N_EDGES + 511) / 512;   // 1172
    const int prep_blocks = (IN_F * OUT_F + N_NODES + 255) / 256;  // 324

    // 0) zero counts + build swizzled bf16 W^T (replaces hipMemsetAsync)
    gcn_prep<<<prep_blocks, 256, 0, stream>>>(w, wt_sw, counts);

    // 1) fused GEMM + histogram (independent workloads co-scheduled)
    gcn_gemm_hist<<<GEMM_BLOCKS + HIST_BLOCKS, 512, 0, stream>>>(
        x, wt_sw, support, erows, counts, rank);

    // 2) block-local exclusive scan -> row_start, partials
    gcn_scan1<<<SCAN_BLOCKS, 256, 0, stream>>>(counts, row_start, partials);

    // 3) absolute block prefix (1 tiny block)
    gcn_scan2<<<1, 256, 0, stream>>>(partials, bp);

    // 4) scatter to row-sorted edge list
    gcn_scatter<<<eblocks512, 512, 0, stream>>>(erows, ecols, evals, row_start,
                                                rank, bp, sorted_cv);

    // 5) aggregate + bias (one wave per node)
    gcn_aggregate_csr<<<(N_NODES * 64 + 511) / 512, 512, 0, stream>>>(
        support, sorted_cv, row_start, bp, bias, out);
}